// Round 17
// baseline (263.519 us; speedup 1.0000x reference)
//
#include <hip/hip_runtime.h>
#include <hip/hip_bf16.h>
#include <math.h>

#define Bb 32
#define Hh 56
#define Ww 56
#define Cc 128
#define HEAD 4
#define WS 7
#define SHIFT 3
#define Nn 49
#define NWw 64
#define HD 32
#define HID 512
#define TOK (Bb*Hh*Ww)
#define SCALEF 0.17677669529663687f
#define WSTRIDE 136   // shorts: 68 dwords %32 = 4 -> 2-way max (free)
#define W2STRIDE 68   // shorts: 34 dwords %32 = 2 -> all 16 rows distinct banks

typedef short short8 __attribute__((ext_vector_type(8)));
typedef float f32x4 __attribute__((ext_vector_type(4)));

__device__ __forceinline__ short f2bf(float f) {
    union { float f; unsigned u; } c; c.f = f;
    unsigned r = (c.u + 0x7fff + ((c.u >> 16) & 1)) >> 16;
    return (short)r;
}
__device__ __forceinline__ unsigned pack2bf(float a, float b) {
    return (unsigned)(unsigned short)f2bf(a) | ((unsigned)(unsigned short)f2bf(b) << 16);
}
// gelu tanh-approx in sigmoid form: 0.5x(1+tanh(y)) == x * sigmoid(2y)
__device__ __forceinline__ float gelu_fast(float x) {
    float p = x * x;
    float v = x * (-1.5957691216f - 0.07135481627f * p);
    float e = __expf(v);
    return x * __builtin_amdgcn_rcpf(1.f + e);
}
__device__ __forceinline__ unsigned cvtpk2bf(float a, float b) {
    unsigned r;
    asm("v_cvt_pk_bf16_f32 %0, %1, %2" : "=v"(r) : "v"(a), "v"(b));
    return r;
}
#define LDS_FENCE() asm volatile("s_waitcnt lgkmcnt(0)" ::: "memory")

// ---------------------------------------------------------------------------
// prep_all: 4x weight transpose + build_table.
// ---------------------------------------------------------------------------
__global__ __launch_bounds__(256) void prep_all(const float* __restrict__ qkvw,
                                                const float* __restrict__ projw,
                                                const float* __restrict__ fc1w,
                                                const float* __restrict__ fc2w,
                                                const float* __restrict__ rpb,
                                                short* __restrict__ qkvwT,
                                                short* __restrict__ projwT,
                                                short* __restrict__ fc1wT,
                                                short* __restrict__ fc2wT,
                                                float* __restrict__ table) {
    int bid = blockIdx.x;
    if (bid < 192) {                     // qkvw: K=128, N=384
        int idx = bid * 256 + threadIdx.x;
        int k = idx / 384, n = idx % 384;
        qkvwT[(size_t)n * 128 + k] = f2bf(qkvw[idx]);
    } else if (bid < 256) {              // projw: K=128, N=128
        int idx = (bid - 192) * 256 + threadIdx.x;
        int k = idx / 128, n = idx % 128;
        projwT[(size_t)n * 128 + k] = f2bf(projw[idx]);
    } else if (bid < 512) {              // fc1w: K=128, N=512
        int idx = (bid - 256) * 256 + threadIdx.x;
        int k = idx / 512, n = idx % 512;
        fc1wT[(size_t)n * 128 + k] = f2bf(fc1w[idx]);
    } else if (bid < 768) {              // fc2w: K=512, N=128
        int idx = (bid - 512) * 256 + threadIdx.x;
        int k = idx / 128, n = idx % 128;
        fc2wT[(size_t)n * 512 + k] = f2bf(fc2w[idx]);
    } else {                             // build_table
        int idx = (bid - 768) * 256 + threadIdx.x;
        int cell = idx & 4095, ch = idx >> 12;
        int cls = ch >> 2, hd = ch & 3;
        int row = cell >> 6, col = cell & 63;
        float v;
        if (row >= Nn || col >= Nn) v = -1e30f;
        else {
            int i1 = row / 7, j1 = row % 7, i2 = col / 7, j2 = col % 7;
            float bias = rpb[((i1 - i2 + 6) * 13 + (j1 - j2 + 6)) * HEAD + hd];
            int bh = cls >> 1, bw = cls & 1;
            int rn = bh ? (i1 < 4 ? 1 : 2) : 0;
            int cn = bw ? (j1 < 4 ? 1 : 2) : 0;
            int rm = bh ? (i2 < 4 ? 1 : 2) : 0;
            int cm = bw ? (j2 < 4 ? 1 : 2) : 0;
            v = bias + (((rn * 3 + cn) != (rm * 3 + cm)) ? -100.f : 0.f);
        }
        table[idx] = v;
    }
}

// ---------------------------------------------------------------------------
// QKV GEMM with FUSED LN1+gather (r16): 8-wave blocks, 128 tokens/block.
// T14 prefetch with post-barrier2 placement (r15).
// ---------------------------------------------------------------------------
__global__ __launch_bounds__(512, 4) void qkv_mfma(const float* __restrict__ x,
                                                   const float* __restrict__ g,
                                                   const float* __restrict__ b,
                                                   const short* __restrict__ wt,
                                                   const float* __restrict__ bias,
                                                   short* __restrict__ qkv) {
    __shared__ short Wc[128 * WSTRIDE];
    int tid = threadIdx.x;
    int wave = tid >> 6, lane = tid & 63;
    int row16 = lane & 15, quad = lane >> 4;
    size_t t0 = (size_t)blockIdx.x * 128 + wave * 16;
    // ---- fused gather + LN1 ----
    int t = (int)t0 + row16;
    int bimg = t / (NWw * Nn);
    int wrow = t % (NWw * Nn);
    int wi = wrow / Nn, nn = wrow % Nn;
    int wh = wi >> 3, ww = wi & 7;
    int ii = nn / 7, jj = nn % 7;
    int sr = (wh * 7 + ii + SHIFT) % Hh;
    int sc = (ww * 7 + jj + SHIFT) % Ww;
    const float* xr = x + ((size_t)bimg * (Hh * Ww) + sr * Ww + sc) * Cc;
    f32x4 xv[8];   // this lane's 32 channels: slice k -> xv[2k], xv[2k+1]
    #pragma unroll
    for (int k = 0; k < 4; ++k) {
        xv[2 * k]     = *(const f32x4*)(xr + k * 32 + quad * 8);
        xv[2 * k + 1] = *(const f32x4*)(xr + k * 32 + quad * 8 + 4);
    }
    float s = 0.f;
    #pragma unroll
    for (int q = 0; q < 8; ++q) s += xv[q][0] + xv[q][1] + xv[q][2] + xv[q][3];
    s += __shfl_xor(s, 16, 64);
    s += __shfl_xor(s, 32, 64);
    float mean = s * (1.f / 128.f);
    float vs = 0.f;
    #pragma unroll
    for (int q = 0; q < 8; ++q) {
        #pragma unroll
        for (int e = 0; e < 4; ++e) { float d = xv[q][e] - mean; vs += d * d; }
    }
    vs += __shfl_xor(vs, 16, 64);
    vs += __shfl_xor(vs, 32, 64);
    float inv = rsqrtf(vs * (1.f / 128.f) + 1e-5f);
    short8 afr[4];
    #pragma unroll
    for (int k = 0; k < 4; ++k) {
        f32x4 g0 = *(const f32x4*)(g + k * 32 + quad * 8);
        f32x4 g1 = *(const f32x4*)(g + k * 32 + quad * 8 + 4);
        f32x4 b0 = *(const f32x4*)(b + k * 32 + quad * 8);
        f32x4 b1v = *(const f32x4*)(b + k * 32 + quad * 8 + 4);
        #pragma unroll
        for (int e = 0; e < 4; ++e) {
            afr[k][e]     = f2bf((xv[2 * k][e] - mean) * inv * g0[e] + b0[e]);
            afr[k][e + 4] = f2bf((xv[2 * k + 1][e] - mean) * inv * g1[e] + b1v[e]);
        }
    }
    // ---- W staging (T14, post-barrier2 prefetch) ----
    short8 wr[4];
    #pragma unroll
    for (int i = 0; i < 4; ++i) {
        int s2 = tid + i * 512;
        wr[i] = *(const short8*)(wt + (size_t)(s2 >> 4) * Cc + (s2 & 15) * 8);
    }
    for (int ch = 0; ch < 3; ++ch) {
        __syncthreads();   // barrier1: all waves done reading prev Wc
        #pragma unroll
        for (int i = 0; i < 4; ++i) {
            int s2 = tid + i * 512;
            *(short8*)(Wc + (s2 >> 4) * WSTRIDE + (s2 & 15) * 8) = wr[i];
        }
        __syncthreads();   // barrier2: no vmem in flight -> no drain stall
        if (ch < 2) {      // issue ch+1 loads now; land under compute
            #pragma unroll
            for (int i = 0; i < 4; ++i) {
                int s2 = tid + i * 512;
                wr[i] = *(const short8*)(wt + (size_t)((ch + 1) * 128 + (s2 >> 4)) * Cc + (s2 & 15) * 8);
            }
        }
        f32x4 acc[8];
        #pragma unroll
        for (int n = 0; n < 8; ++n) acc[n] = (f32x4)(0.f);
        #pragma unroll
        for (int k = 0; k < 4; ++k) {
            #pragma unroll
            for (int n = 0; n < 8; ++n) {
                short8 bfr = *(const short8*)(Wc + (n * 16 + row16) * WSTRIDE + k * 32 + quad * 8);
                acc[n] = __builtin_amdgcn_mfma_f32_16x16x32_bf16(afr[k], bfr, acc[n], 0, 0, 0);
            }
        }
        #pragma unroll
        for (int n = 0; n < 8; ++n) {
            int col = ch * 128 + n * 16 + row16;
            float bv = bias[col];
            #pragma unroll
            for (int r = 0; r < 4; ++r) {
                float val = acc[n][r] + bv;
                if (ch == 0) val *= SCALEF;
                qkv[(t0 + quad * 4 + r) * 384 + col] = f2bf(val);
            }
        }
    }
}

// ---------------------------------------------------------------------------
// MFMA attention (r14): V gathered directly from qkv, issued early; LDS =
// Pbuf only. Token clamp to 48 (P=0 makes duplicate harmless).
// ---------------------------------------------------------------------------
__global__ __launch_bounds__(128, 3) void attn_mfma(const short* __restrict__ qkv,
                                                    const float* __restrict__ table,
                                                    short* __restrict__ o) {
    __shared__ short Pbuf[2][64 * 72];
    int wave = threadIdx.x >> 6, lane = threadIdx.x & 63;
    int row16 = lane & 15, quad = lane >> 4;
    int unit = blockIdx.x * 2 + wave;
    int bw = unit >> 2, hd = unit & 3;
    int widx = bw & 63, wh = widx >> 3, ww = widx & 7;
    int cls = ((wh == 7) ? 2 : 0) | ((ww == 7) ? 1 : 0);
    const float* tb = table + ((size_t)(cls * 4 + hd)) * 4096;
    short* P = &Pbuf[wave][0];
    const short* base = qkv + (size_t)bw * Nn * 384 + hd * HD;

    // V fragments: B[col=d][k=tok] gathered from qkv rows, issued early.
    short8 vb[2][2];
    #pragma unroll
    for (int kt = 0; kt < 2; ++kt)
        #pragma unroll
        for (int nt = 0; nt < 2; ++nt) {
            int d = nt * 16 + row16;
            #pragma unroll
            for (int j = 0; j < 8; ++j) {
                int t = kt * 32 + quad * 8 + j;
                int tc = t < Nn ? t : Nn - 1;
                vb[kt][nt][j] = base[(size_t)tc * 384 + 256 + d];
            }
        }

    short8 qa[4], kb[4];
    #pragma unroll
    for (int mt = 0; mt < 4; ++mt) {
        int r = mt * 16 + row16;
        if (r < Nn) {
            qa[mt] = *(const short8*)(base + (size_t)r * 384 + quad * 8);
            kb[mt] = *(const short8*)(base + (size_t)r * 384 + 128 + quad * 8);
        } else {
            qa[mt] = (short8)(short)0;
            kb[mt] = (short8)(short)0;
        }
    }
    f32x4 s[4][4];
    #pragma unroll
    for (int mt = 0; mt < 4; ++mt)
        #pragma unroll
        for (int nt = 0; nt < 4; ++nt)
            s[mt][nt] = __builtin_amdgcn_mfma_f32_16x16x32_bf16(qa[mt], kb[nt], (f32x4)(0.f), 0, 0, 0);

    #pragma unroll
    for (int mt = 0; mt < 4; ++mt) {
        #pragma unroll
        for (int r = 0; r < 4; ++r) {
            int row = mt * 16 + quad * 4 + r;
            float mx = -1e30f;
            #pragma unroll
            for (int nt = 0; nt < 4; ++nt) {
                s[mt][nt][r] += tb[row * 64 + nt * 16 + row16];
                mx = fmaxf(mx, s[mt][nt][r]);
            }
            #pragma unroll
            for (int m = 1; m < 16; m <<= 1) mx = fmaxf(mx, __shfl_xor(mx, m, 64));
            float sm = 0.f;
            #pragma unroll
            for (int nt = 0; nt < 4; ++nt) {
                float e = __expf(s[mt][nt][r] - mx);
                s[mt][nt][r] = e;
                sm += e;
            }
            #pragma unroll
            for (int m = 1; m < 16; m <<= 1) sm += __shfl_xor(sm, m, 64);
            float inv = 1.f / sm;
            #pragma unroll
            for (int nt = 0; nt < 4; ++nt)
                P[row * 72 + nt * 16 + row16] = f2bf(s[mt][nt][r] * inv);
        }
    }
    LDS_FENCE();

    f32x4 oacc[4][2];
    #pragma unroll
    for (int mt = 0; mt < 4; ++mt)
        #pragma unroll
        for (int nt = 0; nt < 2; ++nt) oacc[mt][nt] = (f32x4)(0.f);
    #pragma unroll
    for (int kt = 0; kt < 2; ++kt) {
        short8 pa[4];
        #pragma unroll
        for (int mt = 0; mt < 4; ++mt)
            pa[mt] = *(const short8*)(P + (mt * 16 + row16) * 72 + kt * 32 + quad * 8);
        #pragma unroll
        for (int mt = 0; mt < 4; ++mt)
            #pragma unroll
            for (int nt = 0; nt < 2; ++nt)
                oacc[mt][nt] = __builtin_amdgcn_mfma_f32_16x16x32_bf16(pa[mt], vb[kt][nt], oacc[mt][nt], 0, 0, 0);
    }
    #pragma unroll
    for (int mt = 0; mt < 4; ++mt)
        #pragma unroll
        for (int nt = 0; nt < 2; ++nt)
            #pragma unroll
            for (int r = 0; r < 4; ++r) {
                int row = mt * 16 + quad * 4 + r;
                if (row < Nn)
                    o[((size_t)bw * Nn + row) * Cc + hd * HD + nt * 16 + row16] = f2bf(oacc[mt][nt][r]);
            }
}

// ---------------------------------------------------------------------------
// Proj: 8-wave blocks (512 thr), 128 tokens/block (16/wave). W staged ONCE
// per block. Scatter + LN2.
// ---------------------------------------------------------------------------
__global__ __launch_bounds__(512, 4) void proj_ln2(const short* __restrict__ o,
                                                   const short* __restrict__ wt,
                                                   const float* __restrict__ pb,
                                                   const float* __restrict__ x,
                                                   const float* __restrict__ g2,
                                                   const float* __restrict__ b2,
                                                   float* __restrict__ x1,
                                                   short* __restrict__ m) {
    __shared__ short Wc[128 * WSTRIDE];
    __shared__ int dest[128];
    int tid = threadIdx.x;
    int wave = tid >> 6, lane = tid & 63;
    int row16 = lane & 15, quad = lane >> 4;
    int s0 = blockIdx.x * 128;
    {
        #pragma unroll
        for (int i = 0; i < 4; ++i) {
            int s = tid + i * 512;
            short8 w = *(const short8*)(wt + (size_t)(s >> 4) * Cc + (s & 15) * 8);
            *(short8*)(Wc + (s >> 4) * WSTRIDE + (s & 15) * 8) = w;
        }
    }
    if (tid < 128) {
        int st = s0 + tid;
        int bimg = st / (NWw * Nn);
        int rem = st % (NWw * Nn);
        int wi = rem / Nn, n = rem % Nn;
        int wh = wi >> 3, ww = wi & 7;
        int i = n / 7, j = n % 7;
        int dr = (wh * 7 + i + SHIFT) % Hh;
        int dc = (ww * 7 + j + SHIFT) % Ww;
        dest[tid] = bimg * (Hh * Ww) + dr * Ww + dc;
    }
    __syncthreads();
    int r0w = wave * 16;
    short8 afr[4];
    #pragma unroll
    for (int k = 0; k < 4; ++k)
        afr[k] = *(const short8*)(o + ((size_t)s0 + r0w + row16) * Cc + k * 32 + quad * 8);
    f32x4 acc[8];
    #pragma unroll
    for (int n = 0; n < 8; ++n) acc[n] = (f32x4)(0.f);
    #pragma unroll
    for (int k = 0; k < 4; ++k) {
        #pragma unroll
        for (int n = 0; n < 8; ++n) {
            short8 bfr = *(const short8*)(Wc + (n * 16 + row16) * WSTRIDE + k * 32 + quad * 8);
            acc[n] = __builtin_amdgcn_mfma_f32_16x16x32_bf16(afr[k], bfr, acc[n], 0, 0, 0);
        }
    }
    float gv[8], bv[8], pbv[8];
    #pragma unroll
    for (int n = 0; n < 8; ++n) {
        int col = n * 16 + row16;
        gv[n] = g2[col]; bv[n] = b2[col]; pbv[n] = pb[col];
    }
    #pragma unroll
    for (int r = 0; r < 4; ++r) {
        int di = dest[r0w + quad * 4 + r];
        #pragma unroll
        for (int n = 0; n < 8; ++n)
            acc[n][r] += x[(size_t)di * Cc + n * 16 + row16] + pbv[n];
        float sum = 0.f;
        #pragma unroll
        for (int n = 0; n < 8; ++n) sum += acc[n][r];
        #pragma unroll
        for (int mk = 1; mk < 16; mk <<= 1) sum += __shfl_xor(sum, mk, 64);
        float mean = sum * (1.f / 128.f);
        float var = 0.f;
        #pragma unroll
        for (int n = 0; n < 8; ++n) {
            float d = acc[n][r] - mean;
            var += d * d;
        }
        #pragma unroll
        for (int mk = 1; mk < 16; mk <<= 1) var += __shfl_xor(var, mk, 64);
        float inv = rsqrtf(var * (1.f / 128.f) + 1e-5f);
        #pragma unroll
        for (int n = 0; n < 8; ++n) {
            size_t idx = (size_t)di * Cc + n * 16 + row16;
            float v = acc[n][r];
            x1[idx] = v;
            m[idx] = f2bf((v - mean) * inv * gv[n] + bv[n]);
        }
    }
}

// ---------------------------------------------------------------------------
// Fused MLP: r15 config + Hs ELIMINATED. The GELU->FC2 hand-off is a pure
// intra-wave permutation: thread (row16,q) holds hid cols {mt*16+q*4+e} of
// token row16; FC2 needs {kk*32+q*8..+8}. Redistribute packed bf16 pairs
// via __shfl from lanes row16+32(q&1) and +16, tile mt'=2kk+(q>>1) selected
// by (q>>1). Deletes Hs (LDS 44->34.8 KB -> 4 blocks/CU, 16 waves) and both
// per-chunk LDS_FENCEs. Values bit-identical (same cvtpk outputs).
// ---------------------------------------------------------------------------
__global__ __launch_bounds__(256, 4) void mlp_mfma(const short* __restrict__ m,
                                                   const short* __restrict__ w1t,
                                                   const float* __restrict__ b1,
                                                   const short* __restrict__ w2t,
                                                   const float* __restrict__ b2,
                                                   const float* __restrict__ x1,
                                                   float* __restrict__ out) {
    __shared__ short W1c[64 * WSTRIDE];
    __shared__ short W2c[128 * W2STRIDE];
    int tid = threadIdx.x;
    int lane = tid & 63;
    int row16 = lane & 15, quad = lane >> 4;
    int wave = tid >> 6;
    size_t t0 = (size_t)blockIdx.x * 64 + wave * 16;
    short8 bfr[4];
    #pragma unroll
    for (int k = 0; k < 4; ++k)
        bfr[k] = *(const short8*)(m + (t0 + row16) * Cc + k * 32 + quad * 8);
    f32x4 acc2[8];
    #pragma unroll
    for (int n = 0; n < 8; ++n) acc2[n] = (f32x4)(0.f);

    int rA = tid >> 4, cA = (tid & 15) * 8;   // W1: 64 rows x 128 shorts
    int rB = tid >> 3, cB = (tid & 7) * 8;    // W2: 128 rows x 64 shorts
    short8 w1r[4], w2r[4];
    #pragma unroll
    for (int i = 0; i < 4; ++i) {
        w1r[i] = *(const short8*)(w1t + (size_t)(rA + i * 16) * Cc + cA);
        w2r[i] = *(const short8*)(w2t + (size_t)(rB + i * 32) * HID + cB);
    }

    int src0 = row16 + 32 * (quad & 1);   // lane holding hid +0..+3 (packed)
    int src1 = src0 + 16;                 // lane holding hid +4..+7
    bool hi = (quad & 2) != 0;            // tile select: mt' = 2kk + (q>>1)

    for (int ch = 0; ch < 8; ++ch) {
        __syncthreads();   // barrier1: all waves done reading prev W1c/W2c
        #pragma unroll
        for (int i = 0; i < 4; ++i) {
            *(short8*)(W1c + (rA + i * 16) * WSTRIDE + cA) = w1r[i];
            *(short8*)(W2c + (rB + i * 32) * W2STRIDE + cB) = w2r[i];
        }
        __syncthreads();   // barrier2: no vmem in flight -> no drain stall
        if (ch < 7) {      // issue ch+1 loads; land under this chunk's compute
            #pragma unroll
            for (int i = 0; i < 4; ++i) {
                w1r[i] = *(const short8*)(w1t + (size_t)((ch + 1) * 64 + rA + i * 16) * Cc + cA);
                w2r[i] = *(const short8*)(w2t + (size_t)(rB + i * 32) * HID + (ch + 1) * 64 + cB);
            }
        }
        // FC1: C[m=hid(64)][n=tok(16)]
        f32x4 acc1[4];
        #pragma unroll
        for (int mt = 0; mt < 4; ++mt) acc1[mt] = (f32x4)(0.f);
        #pragma unroll
        for (int k = 0; k < 4; ++k) {
            #pragma unroll
            for (int mt = 0; mt < 4; ++mt) {
                short8 a = *(const short8*)(W1c + (mt * 16 + row16) * WSTRIDE + k * 32 + quad * 8);
                acc1[mt] = __builtin_amdgcn_mfma_f32_16x16x32_bf16(a, bfr[k], acc1[mt], 0, 0, 0);
            }
        }
        // GELU -> packed bf16 pairs kept in REGISTERS (no LDS)
        unsigned pkx[4], pky[4];
        #pragma unroll
        for (int mt = 0; mt < 4; ++mt) {
            int hidb = ch * 64 + mt * 16 + quad * 4;
            f32x4 b1v = *(const f32x4*)(b1 + hidb);
            float h0 = gelu_fast(acc1[mt][0] + b1v[0]);
            float h1 = gelu_fast(acc1[mt][1] + b1v[1]);
            float h2 = gelu_fast(acc1[mt][2] + b1v[2]);
            float h3 = gelu_fast(acc1[mt][3] + b1v[3]);
            pkx[mt] = cvtpk2bf(h0, h1);
            pky[mt] = cvtpk2bf(h2, h3);
        }
        // FC2: cross-quad redistribution in-register; then MFMA over W2c
        #pragma unroll
        for (int kk = 0; kk < 2; ++kk) {
            unsigned a0l = __shfl(pkx[2 * kk],     src0, 64);
            unsigned a0h = __shfl(pkx[2 * kk + 1], src0, 64);
            unsigned a1l = __shfl(pky[2 * kk],     src0, 64);
            unsigned a1h = __shfl(pky[2 * kk + 1], src0, 64);
            unsigned a2l = __shfl(pkx[2 * kk],     src1, 64);
            unsigned a2h = __shfl(pkx[2 * kk + 1], src1, 64);
            unsigned a3l = __shfl(pky[2 * kk],     src1, 64);
            unsigned a3h = __shfl(pky[2 * kk + 1], src1, 64);
            union { unsigned u[4]; short8 s8; } hu;
            hu.u[0] = hi ? a0h : a0l;
            hu.u[1] = hi ? a1h : a1l;
            hu.u[2] = hi ? a2h : a2l;
            hu.u[3] = hi ? a3h : a3l;
            short8 ha = hu.s8;
            #pragma unroll
            for (int n = 0; n < 8; ++n) {
                short8 wb = *(const short8*)(W2c + (n * 16 + row16) * W2STRIDE + kk * 32 + quad * 8);
                acc2[n] = __builtin_amdgcn_mfma_f32_16x16x32_bf16(ha, wb, acc2[n], 0, 0, 0);
            }
        }
    }
    #pragma unroll
    for (int n = 0; n < 8; ++n) {
        int col = n * 16 + row16;
        float bb = b2[col];
        #pragma unroll
        for (int r = 0; r < 4; ++r) {
            size_t idx = (t0 + quad * 4 + r) * Cc + col;
            out[idx] = x1[idx] + bb + acc2[n][r];
        }
    }
}

// ---------------------------------------------------------------------------
extern "C" void kernel_launch(void* const* d_in, const int* in_sizes, int n_in,
                              void* d_out, int out_size, void* d_ws, size_t ws_size,
                              hipStream_t stream) {
    const float* x     = (const float*)d_in[0];
    const float* n1g   = (const float*)d_in[1];
    const float* n1b   = (const float*)d_in[2];
    const float* qkvw  = (const float*)d_in[3];
    const float* qkvb  = (const float*)d_in[4];
    const float* projw = (const float*)d_in[5];
    const float* projb = (const float*)d_in[6];
    const float* rpb   = (const float*)d_in[7];
    const float* n2g   = (const float*)d_in[8];
    const float* n2b   = (const float*)d_in[9];
    const float* fc1w  = (const float*)d_in[10];
    const float* fc1b  = (const float*)d_in[11];
    const float* fc2w  = (const float*)d_in[12];
    const float* fc2b  = (const float*)d_in[13];
    float* out = (float*)d_out;

    char* ws = (char*)d_ws;
    short* qkv   = (short*)ws;
    float* x1    = (float*)(ws + 77070336);
    float* table = x1;  // dead until proj_ln2 writes x1 (attn reads it first)
    short* h     = (short*)(ws + 77070336 + 51380224);
    short* m     = h;   // m written by proj_ln2, read by mlp
    short* o     = (short*)(ws + 77070336 + 51380224 + 25690112);
    short* qkvwT = (short*)(ws + 77070336 + 51380224 + 2 * 25690112);
    short* projwT= qkvwT + 384 * 128;
    short* fc1wT = projwT + 128 * 128;
    short* fc2wT = fc1wT + 512 * 128;

    prep_all<<<1024, 256, 0, stream>>>(qkvw, projw, fc1w, fc2w, rpb,
                                       qkvwT, projwT, fc1wT, fc2wT, table);
    qkv_mfma<<<TOK / 128, 512, 0, stream>>>(x, n1g, n1b, qkvwT, qkvb, qkv);
    attn_mfma<<<(TOK / Nn) * HEAD / 2, 128, 0, stream>>>(qkv, table, o);
    proj_ln2<<<TOK / 128, 512, 0, stream>>>(o, projwT, projb, x, n2g, n2b, x1, m);
    mlp_mfma<<<TOK / 64, 256, 0, stream>>>(m, fc1wT, fc1b, fc2wT, fc2b, x1, out);
}

// Round 18
// 258.363 us; speedup vs baseline: 1.0200x; 1.0200x over previous
//
#include <hip/hip_runtime.h>
#include <hip/hip_bf16.h>
#include <math.h>

#define Bb 32
#define Hh 56
#define Ww 56
#define Cc 128
#define HEAD 4
#define WS 7
#define SHIFT 3
#define Nn 49
#define NWw 64
#define HD 32
#define HID 512
#define TOK (Bb*Hh*Ww)
#define SCALEF 0.17677669529663687f
#define WSTRIDE 136   // shorts: 68 dwords %32 = 4 -> 2-way max (free)
#define W2STRIDE 68   // shorts: 34 dwords %32 = 2 -> all 16 rows distinct banks

typedef short short8 __attribute__((ext_vector_type(8)));
typedef float f32x4 __attribute__((ext_vector_type(4)));

__device__ __forceinline__ short f2bf(float f) {
    union { float f; unsigned u; } c; c.f = f;
    unsigned r = (c.u + 0x7fff + ((c.u >> 16) & 1)) >> 16;
    return (short)r;
}
__device__ __forceinline__ unsigned pack2bf(float a, float b) {
    return (unsigned)(unsigned short)f2bf(a) | ((unsigned)(unsigned short)f2bf(b) << 16);
}
// gelu tanh-approx in sigmoid form: 0.5x(1+tanh(y)) == x * sigmoid(2y)
__device__ __forceinline__ float gelu_fast(float x) {
    float p = x * x;
    float v = x * (-1.5957691216f - 0.07135481627f * p);
    float e = __expf(v);
    return x * __builtin_amdgcn_rcpf(1.f + e);
}
__device__ __forceinline__ unsigned cvtpk2bf(float a, float b) {
    unsigned r;
    asm("v_cvt_pk_bf16_f32 %0, %1, %2" : "=v"(r) : "v"(a), "v"(b));
    return r;
}
#define LDS_FENCE() asm volatile("s_waitcnt lgkmcnt(0)" ::: "memory")

// ---------------------------------------------------------------------------
// prep_all: 4x weight transpose + build_table.
// ---------------------------------------------------------------------------
__global__ __launch_bounds__(256) void prep_all(const float* __restrict__ qkvw,
                                                const float* __restrict__ projw,
                                                const float* __restrict__ fc1w,
                                                const float* __restrict__ fc2w,
                                                const float* __restrict__ rpb,
                                                short* __restrict__ qkvwT,
                                                short* __restrict__ projwT,
                                                short* __restrict__ fc1wT,
                                                short* __restrict__ fc2wT,
                                                float* __restrict__ table) {
    int bid = blockIdx.x;
    if (bid < 192) {                     // qkvw: K=128, N=384
        int idx = bid * 256 + threadIdx.x;
        int k = idx / 384, n = idx % 384;
        qkvwT[(size_t)n * 128 + k] = f2bf(qkvw[idx]);
    } else if (bid < 256) {              // projw: K=128, N=128
        int idx = (bid - 192) * 256 + threadIdx.x;
        int k = idx / 128, n = idx % 128;
        projwT[(size_t)n * 128 + k] = f2bf(projw[idx]);
    } else if (bid < 512) {              // fc1w: K=128, N=512
        int idx = (bid - 256) * 256 + threadIdx.x;
        int k = idx / 512, n = idx % 512;
        fc1wT[(size_t)n * 128 + k] = f2bf(fc1w[idx]);
    } else if (bid < 768) {              // fc2w: K=512, N=128
        int idx = (bid - 512) * 256 + threadIdx.x;
        int k = idx / 128, n = idx % 128;
        fc2wT[(size_t)n * 512 + k] = f2bf(fc2w[idx]);
    } else {                             // build_table
        int idx = (bid - 768) * 256 + threadIdx.x;
        int cell = idx & 4095, ch = idx >> 12;
        int cls = ch >> 2, hd = ch & 3;
        int row = cell >> 6, col = cell & 63;
        float v;
        if (row >= Nn || col >= Nn) v = -1e30f;
        else {
            int i1 = row / 7, j1 = row % 7, i2 = col / 7, j2 = col % 7;
            float bias = rpb[((i1 - i2 + 6) * 13 + (j1 - j2 + 6)) * HEAD + hd];
            int bh = cls >> 1, bw = cls & 1;
            int rn = bh ? (i1 < 4 ? 1 : 2) : 0;
            int cn = bw ? (j1 < 4 ? 1 : 2) : 0;
            int rm = bh ? (i2 < 4 ? 1 : 2) : 0;
            int cm = bw ? (j2 < 4 ? 1 : 2) : 0;
            v = bias + (((rn * 3 + cn) != (rm * 3 + cm)) ? -100.f : 0.f);
        }
        table[idx] = v;
    }
}

// ---------------------------------------------------------------------------
// QKV GEMM with FUSED LN1+gather (r16): 8-wave blocks, 128 tokens/block.
// T14 prefetch with post-barrier2 placement (r15).
// ---------------------------------------------------------------------------
__global__ __launch_bounds__(512, 4) void qkv_mfma(const float* __restrict__ x,
                                                   const float* __restrict__ g,
                                                   const float* __restrict__ b,
                                                   const short* __restrict__ wt,
                                                   const float* __restrict__ bias,
                                                   short* __restrict__ qkv) {
    __shared__ short Wc[128 * WSTRIDE];
    int tid = threadIdx.x;
    int wave = tid >> 6, lane = tid & 63;
    int row16 = lane & 15, quad = lane >> 4;
    size_t t0 = (size_t)blockIdx.x * 128 + wave * 16;
    // ---- fused gather + LN1 ----
    int t = (int)t0 + row16;
    int bimg = t / (NWw * Nn);
    int wrow = t % (NWw * Nn);
    int wi = wrow / Nn, nn = wrow % Nn;
    int wh = wi >> 3, ww = wi & 7;
    int ii = nn / 7, jj = nn % 7;
    int sr = (wh * 7 + ii + SHIFT) % Hh;
    int sc = (ww * 7 + jj + SHIFT) % Ww;
    const float* xr = x + ((size_t)bimg * (Hh * Ww) + sr * Ww + sc) * Cc;
    f32x4 xv[8];   // this lane's 32 channels: slice k -> xv[2k], xv[2k+1]
    #pragma unroll
    for (int k = 0; k < 4; ++k) {
        xv[2 * k]     = *(const f32x4*)(xr + k * 32 + quad * 8);
        xv[2 * k + 1] = *(const f32x4*)(xr + k * 32 + quad * 8 + 4);
    }
    float s = 0.f;
    #pragma unroll
    for (int q = 0; q < 8; ++q) s += xv[q][0] + xv[q][1] + xv[q][2] + xv[q][3];
    s += __shfl_xor(s, 16, 64);
    s += __shfl_xor(s, 32, 64);
    float mean = s * (1.f / 128.f);
    float vs = 0.f;
    #pragma unroll
    for (int q = 0; q < 8; ++q) {
        #pragma unroll
        for (int e = 0; e < 4; ++e) { float d = xv[q][e] - mean; vs += d * d; }
    }
    vs += __shfl_xor(vs, 16, 64);
    vs += __shfl_xor(vs, 32, 64);
    float inv = rsqrtf(vs * (1.f / 128.f) + 1e-5f);
    short8 afr[4];
    #pragma unroll
    for (int k = 0; k < 4; ++k) {
        f32x4 g0 = *(const f32x4*)(g + k * 32 + quad * 8);
        f32x4 g1 = *(const f32x4*)(g + k * 32 + quad * 8 + 4);
        f32x4 b0 = *(const f32x4*)(b + k * 32 + quad * 8);
        f32x4 b1v = *(const f32x4*)(b + k * 32 + quad * 8 + 4);
        #pragma unroll
        for (int e = 0; e < 4; ++e) {
            afr[k][e]     = f2bf((xv[2 * k][e] - mean) * inv * g0[e] + b0[e]);
            afr[k][e + 4] = f2bf((xv[2 * k + 1][e] - mean) * inv * g1[e] + b1v[e]);
        }
    }
    // ---- W staging (T14, post-barrier2 prefetch) ----
    short8 wr[4];
    #pragma unroll
    for (int i = 0; i < 4; ++i) {
        int s2 = tid + i * 512;
        wr[i] = *(const short8*)(wt + (size_t)(s2 >> 4) * Cc + (s2 & 15) * 8);
    }
    for (int ch = 0; ch < 3; ++ch) {
        __syncthreads();   // barrier1: all waves done reading prev Wc
        #pragma unroll
        for (int i = 0; i < 4; ++i) {
            int s2 = tid + i * 512;
            *(short8*)(Wc + (s2 >> 4) * WSTRIDE + (s2 & 15) * 8) = wr[i];
        }
        __syncthreads();   // barrier2: no vmem in flight -> no drain stall
        if (ch < 2) {      // issue ch+1 loads now; land under compute
            #pragma unroll
            for (int i = 0; i < 4; ++i) {
                int s2 = tid + i * 512;
                wr[i] = *(const short8*)(wt + (size_t)((ch + 1) * 128 + (s2 >> 4)) * Cc + (s2 & 15) * 8);
            }
        }
        f32x4 acc[8];
        #pragma unroll
        for (int n = 0; n < 8; ++n) acc[n] = (f32x4)(0.f);
        #pragma unroll
        for (int k = 0; k < 4; ++k) {
            #pragma unroll
            for (int n = 0; n < 8; ++n) {
                short8 bfr = *(const short8*)(Wc + (n * 16 + row16) * WSTRIDE + k * 32 + quad * 8);
                acc[n] = __builtin_amdgcn_mfma_f32_16x16x32_bf16(afr[k], bfr, acc[n], 0, 0, 0);
            }
        }
        #pragma unroll
        for (int n = 0; n < 8; ++n) {
            int col = ch * 128 + n * 16 + row16;
            float bv = bias[col];
            #pragma unroll
            for (int r = 0; r < 4; ++r) {
                float val = acc[n][r] + bv;
                if (ch == 0) val *= SCALEF;
                qkv[(t0 + quad * 4 + r) * 384 + col] = f2bf(val);
            }
        }
    }
}

// ---------------------------------------------------------------------------
// MFMA attention (r14): V gathered directly from qkv, issued early; LDS =
// Pbuf only. Token clamp to 48 (P=0 makes duplicate harmless).
// ---------------------------------------------------------------------------
__global__ __launch_bounds__(128, 3) void attn_mfma(const short* __restrict__ qkv,
                                                    const float* __restrict__ table,
                                                    short* __restrict__ o) {
    __shared__ short Pbuf[2][64 * 72];
    int wave = threadIdx.x >> 6, lane = threadIdx.x & 63;
    int row16 = lane & 15, quad = lane >> 4;
    int unit = blockIdx.x * 2 + wave;
    int bw = unit >> 2, hd = unit & 3;
    int widx = bw & 63, wh = widx >> 3, ww = widx & 7;
    int cls = ((wh == 7) ? 2 : 0) | ((ww == 7) ? 1 : 0);
    const float* tb = table + ((size_t)(cls * 4 + hd)) * 4096;
    short* P = &Pbuf[wave][0];
    const short* base = qkv + (size_t)bw * Nn * 384 + hd * HD;

    // V fragments: B[col=d][k=tok] gathered from qkv rows, issued early.
    short8 vb[2][2];
    #pragma unroll
    for (int kt = 0; kt < 2; ++kt)
        #pragma unroll
        for (int nt = 0; nt < 2; ++nt) {
            int d = nt * 16 + row16;
            #pragma unroll
            for (int j = 0; j < 8; ++j) {
                int t = kt * 32 + quad * 8 + j;
                int tc = t < Nn ? t : Nn - 1;
                vb[kt][nt][j] = base[(size_t)tc * 384 + 256 + d];
            }
        }

    short8 qa[4], kb[4];
    #pragma unroll
    for (int mt = 0; mt < 4; ++mt) {
        int r = mt * 16 + row16;
        if (r < Nn) {
            qa[mt] = *(const short8*)(base + (size_t)r * 384 + quad * 8);
            kb[mt] = *(const short8*)(base + (size_t)r * 384 + 128 + quad * 8);
        } else {
            qa[mt] = (short8)(short)0;
            kb[mt] = (short8)(short)0;
        }
    }
    f32x4 s[4][4];
    #pragma unroll
    for (int mt = 0; mt < 4; ++mt)
        #pragma unroll
        for (int nt = 0; nt < 4; ++nt)
            s[mt][nt] = __builtin_amdgcn_mfma_f32_16x16x32_bf16(qa[mt], kb[nt], (f32x4)(0.f), 0, 0, 0);

    #pragma unroll
    for (int mt = 0; mt < 4; ++mt) {
        #pragma unroll
        for (int r = 0; r < 4; ++r) {
            int row = mt * 16 + quad * 4 + r;
            float mx = -1e30f;
            #pragma unroll
            for (int nt = 0; nt < 4; ++nt) {
                s[mt][nt][r] += tb[row * 64 + nt * 16 + row16];
                mx = fmaxf(mx, s[mt][nt][r]);
            }
            #pragma unroll
            for (int m = 1; m < 16; m <<= 1) mx = fmaxf(mx, __shfl_xor(mx, m, 64));
            float sm = 0.f;
            #pragma unroll
            for (int nt = 0; nt < 4; ++nt) {
                float e = __expf(s[mt][nt][r] - mx);
                s[mt][nt][r] = e;
                sm += e;
            }
            #pragma unroll
            for (int m = 1; m < 16; m <<= 1) sm += __shfl_xor(sm, m, 64);
            float inv = 1.f / sm;
            #pragma unroll
            for (int nt = 0; nt < 4; ++nt)
                P[row * 72 + nt * 16 + row16] = f2bf(s[mt][nt][r] * inv);
        }
    }
    LDS_FENCE();

    f32x4 oacc[4][2];
    #pragma unroll
    for (int mt = 0; mt < 4; ++mt)
        #pragma unroll
        for (int nt = 0; nt < 2; ++nt) oacc[mt][nt] = (f32x4)(0.f);
    #pragma unroll
    for (int kt = 0; kt < 2; ++kt) {
        short8 pa[4];
        #pragma unroll
        for (int mt = 0; mt < 4; ++mt)
            pa[mt] = *(const short8*)(P + (mt * 16 + row16) * 72 + kt * 32 + quad * 8);
        #pragma unroll
        for (int mt = 0; mt < 4; ++mt)
            #pragma unroll
            for (int nt = 0; nt < 2; ++nt)
                oacc[mt][nt] = __builtin_amdgcn_mfma_f32_16x16x32_bf16(pa[mt], vb[kt][nt], oacc[mt][nt], 0, 0, 0);
    }
    #pragma unroll
    for (int mt = 0; mt < 4; ++mt)
        #pragma unroll
        for (int nt = 0; nt < 2; ++nt)
            #pragma unroll
            for (int r = 0; r < 4; ++r) {
                int row = mt * 16 + quad * 4 + r;
                if (row < Nn)
                    o[((size_t)bw * Nn + row) * Cc + hd * HD + nt * 16 + row16] = f2bf(oacc[mt][nt][r]);
            }
}

// ---------------------------------------------------------------------------
// Proj: 8-wave blocks (512 thr), 128 tokens/block (16/wave). W staged ONCE
// per block. Scatter + LN2.
// ---------------------------------------------------------------------------
__global__ __launch_bounds__(512, 4) void proj_ln2(const short* __restrict__ o,
                                                   const short* __restrict__ wt,
                                                   const float* __restrict__ pb,
                                                   const float* __restrict__ x,
                                                   const float* __restrict__ g2,
                                                   const float* __restrict__ b2,
                                                   float* __restrict__ x1,
                                                   short* __restrict__ m) {
    __shared__ short Wc[128 * WSTRIDE];
    __shared__ int dest[128];
    int tid = threadIdx.x;
    int wave = tid >> 6, lane = tid & 63;
    int row16 = lane & 15, quad = lane >> 4;
    int s0 = blockIdx.x * 128;
    {
        #pragma unroll
        for (int i = 0; i < 4; ++i) {
            int s = tid + i * 512;
            short8 w = *(const short8*)(wt + (size_t)(s >> 4) * Cc + (s & 15) * 8);
            *(short8*)(Wc + (s >> 4) * WSTRIDE + (s & 15) * 8) = w;
        }
    }
    if (tid < 128) {
        int st = s0 + tid;
        int bimg = st / (NWw * Nn);
        int rem = st % (NWw * Nn);
        int wi = rem / Nn, n = rem % Nn;
        int wh = wi >> 3, ww = wi & 7;
        int i = n / 7, j = n % 7;
        int dr = (wh * 7 + i + SHIFT) % Hh;
        int dc = (ww * 7 + j + SHIFT) % Ww;
        dest[tid] = bimg * (Hh * Ww) + dr * Ww + dc;
    }
    __syncthreads();
    int r0w = wave * 16;
    short8 afr[4];
    #pragma unroll
    for (int k = 0; k < 4; ++k)
        afr[k] = *(const short8*)(o + ((size_t)s0 + r0w + row16) * Cc + k * 32 + quad * 8);
    f32x4 acc[8];
    #pragma unroll
    for (int n = 0; n < 8; ++n) acc[n] = (f32x4)(0.f);
    #pragma unroll
    for (int k = 0; k < 4; ++k) {
        #pragma unroll
        for (int n = 0; n < 8; ++n) {
            short8 bfr = *(const short8*)(Wc + (n * 16 + row16) * WSTRIDE + k * 32 + quad * 8);
            acc[n] = __builtin_amdgcn_mfma_f32_16x16x32_bf16(afr[k], bfr, acc[n], 0, 0, 0);
        }
    }
    float gv[8], bv[8], pbv[8];
    #pragma unroll
    for (int n = 0; n < 8; ++n) {
        int col = n * 16 + row16;
        gv[n] = g2[col]; bv[n] = b2[col]; pbv[n] = pb[col];
    }
    #pragma unroll
    for (int r = 0; r < 4; ++r) {
        int di = dest[r0w + quad * 4 + r];
        #pragma unroll
        for (int n = 0; n < 8; ++n)
            acc[n][r] += x[(size_t)di * Cc + n * 16 + row16] + pbv[n];
        float sum = 0.f;
        #pragma unroll
        for (int n = 0; n < 8; ++n) sum += acc[n][r];
        #pragma unroll
        for (int mk = 1; mk < 16; mk <<= 1) sum += __shfl_xor(sum, mk, 64);
        float mean = sum * (1.f / 128.f);
        float var = 0.f;
        #pragma unroll
        for (int n = 0; n < 8; ++n) {
            float d = acc[n][r] - mean;
            var += d * d;
        }
        #pragma unroll
        for (int mk = 1; mk < 16; mk <<= 1) var += __shfl_xor(var, mk, 64);
        float inv = rsqrtf(var * (1.f / 128.f) + 1e-5f);
        #pragma unroll
        for (int n = 0; n < 8; ++n) {
            size_t idx = (size_t)di * Cc + n * 16 + row16;
            float v = acc[n][r];
            x1[idx] = v;
            m[idx] = f2bf((v - mean) * inv * gv[n] + bv[n]);
        }
    }
}

// ---------------------------------------------------------------------------
// Fused MLP (r16 proven, 63.8-64.4 µs): 4 waves, 64 tok/block, LB(256,3),
// Hs LDS hand-off, corrected T14 prefetch (post-barrier2). r17's shuffle
// variant measured worse (67.5): the 8-shfl chain sits serially before each
// MFMA, while Hs latency is wave-overlapped. Critical-path-bound; occupancy
// levers (r6/r8/r17) all measured negative.
// ---------------------------------------------------------------------------
#define HSTRIDE 72
__global__ __launch_bounds__(256, 3) void mlp_mfma(const short* __restrict__ m,
                                                   const short* __restrict__ w1t,
                                                   const float* __restrict__ b1,
                                                   const short* __restrict__ w2t,
                                                   const float* __restrict__ b2,
                                                   const float* __restrict__ x1,
                                                   float* __restrict__ out) {
    __shared__ short W1c[64 * WSTRIDE];
    __shared__ short W2c[128 * W2STRIDE];
    __shared__ short Hs[4][16 * HSTRIDE];
    int tid = threadIdx.x;
    int wave = tid >> 6, lane = tid & 63;
    int row16 = lane & 15, quad = lane >> 4;
    size_t t0 = (size_t)blockIdx.x * 64 + wave * 16;
    short* Ht = &Hs[wave][0];
    short8 bfr[4];
    #pragma unroll
    for (int k = 0; k < 4; ++k)
        bfr[k] = *(const short8*)(m + (t0 + row16) * Cc + k * 32 + quad * 8);
    f32x4 acc2[8];
    #pragma unroll
    for (int n = 0; n < 8; ++n) acc2[n] = (f32x4)(0.f);

    int rA = tid >> 4, cA = (tid & 15) * 8;   // W1: 64 rows x 128 shorts
    int rB = tid >> 3, cB = (tid & 7) * 8;    // W2: 128 rows x 64 shorts
    short8 w1r[4], w2r[4];
    #pragma unroll
    for (int i = 0; i < 4; ++i) {
        w1r[i] = *(const short8*)(w1t + (size_t)(rA + i * 16) * Cc + cA);
        w2r[i] = *(const short8*)(w2t + (size_t)(rB + i * 32) * HID + cB);
    }

    for (int ch = 0; ch < 8; ++ch) {
        __syncthreads();   // barrier1: all waves done reading prev W1c/W2c
        #pragma unroll
        for (int i = 0; i < 4; ++i) {
            *(short8*)(W1c + (rA + i * 16) * WSTRIDE + cA) = w1r[i];
            *(short8*)(W2c + (rB + i * 32) * W2STRIDE + cB) = w2r[i];
        }
        __syncthreads();   // barrier2: no vmem in flight -> no drain stall
        if (ch < 7) {      // issue ch+1 loads now; land under this chunk's compute
            #pragma unroll
            for (int i = 0; i < 4; ++i) {
                w1r[i] = *(const short8*)(w1t + (size_t)((ch + 1) * 64 + rA + i * 16) * Cc + cA);
                w2r[i] = *(const short8*)(w2t + (size_t)(rB + i * 32) * HID + (ch + 1) * 64 + cB);
            }
        }
        f32x4 acc1[4];
        #pragma unroll
        for (int mt = 0; mt < 4; ++mt) acc1[mt] = (f32x4)(0.f);
        #pragma unroll
        for (int k = 0; k < 4; ++k) {
            #pragma unroll
            for (int mt = 0; mt < 4; ++mt) {
                short8 a = *(const short8*)(W1c + (mt * 16 + row16) * WSTRIDE + k * 32 + quad * 8);
                acc1[mt] = __builtin_amdgcn_mfma_f32_16x16x32_bf16(a, bfr[k], acc1[mt], 0, 0, 0);
            }
        }
        #pragma unroll
        for (int mt = 0; mt < 4; ++mt) {
            int hidb = ch * 64 + mt * 16 + quad * 4;
            f32x4 b1v = *(const f32x4*)(b1 + hidb);
            float h0 = gelu_fast(acc1[mt][0] + b1v[0]);
            float h1 = gelu_fast(acc1[mt][1] + b1v[1]);
            float h2 = gelu_fast(acc1[mt][2] + b1v[2]);
            float h3 = gelu_fast(acc1[mt][3] + b1v[3]);
            uint2 pk;
            pk.x = cvtpk2bf(h0, h1);
            pk.y = cvtpk2bf(h2, h3);
            *(uint2*)(Ht + row16 * HSTRIDE + mt * 16 + quad * 4) = pk;
        }
        LDS_FENCE();
        #pragma unroll
        for (int kk = 0; kk < 2; ++kk) {
            short8 ha = *(const short8*)(Ht + row16 * HSTRIDE + kk * 32 + quad * 8);
            #pragma unroll
            for (int n = 0; n < 8; ++n) {
                short8 wb = *(const short8*)(W2c + (n * 16 + row16) * W2STRIDE + kk * 32 + quad * 8);
                acc2[n] = __builtin_amdgcn_mfma_f32_16x16x32_bf16(ha, wb, acc2[n], 0, 0, 0);
            }
        }
        LDS_FENCE();
    }
    #pragma unroll
    for (int n = 0; n < 8; ++n) {
        int col = n * 16 + row16;
        float bb = b2[col];
        #pragma unroll
        for (int r = 0; r < 4; ++r) {
            size_t idx = (t0 + quad * 4 + r) * Cc + col;
            out[idx] = x1[idx] + bb + acc2[n][r];
        }
    }
}

// ---------------------------------------------------------------------------
extern "C" void kernel_launch(void* const* d_in, const int* in_sizes, int n_in,
                              void* d_out, int out_size, void* d_ws, size_t ws_size,
                              hipStream_t stream) {
    const float* x     = (const float*)d_in[0];
    const float* n1g   = (const float*)d_in[1];
    const float* n1b   = (const float*)d_in[2];
    const float* qkvw  = (const float*)d_in[3];
    const float* qkvb  = (const float*)d_in[4];
    const float* projw = (const float*)d_in[5];
    const float* projb = (const float*)d_in[6];
    const float* rpb   = (const float*)d_in[7];
    const float* n2g   = (const float*)d_in[8];
    const float* n2b   = (const float*)d_in[9];
    const float* fc1w  = (const float*)d_in[10];
    const float* fc1b  = (const float*)d_in[11];
    const float* fc2w  = (const float*)d_in[12];
    const float* fc2b  = (const float*)d_in[13];
    float* out = (float*)d_out;

    char* ws = (char*)d_ws;
    short* qkv   = (short*)ws;
    float* x1    = (float*)(ws + 77070336);
    float* table = x1;  // dead until proj_ln2 writes x1 (attn reads it first)
    short* h     = (short*)(ws + 77070336 + 51380224);
    short* m     = h;   // m written by proj_ln2, read by mlp
    short* o     = (short*)(ws + 77070336 + 51380224 + 25690112);
    short* qkvwT = (short*)(ws + 77070336 + 51380224 + 2 * 25690112);
    short* projwT= qkvwT + 384 * 128;
    short* fc1wT = projwT + 128 * 128;
    short* fc2wT = fc1wT + 512 * 128;

    prep_all<<<1024, 256, 0, stream>>>(qkvw, projw, fc1w, fc2w, rpb,
                                       qkvwT, projwT, fc1wT, fc2wT, table);
    qkv_mfma<<<TOK / 128, 512, 0, stream>>>(x, n1g, n1b, qkvwT, qkvb, qkv);
    attn_mfma<<<(TOK / Nn) * HEAD / 2, 128, 0, stream>>>(qkv, table, o);
    proj_ln2<<<TOK / 128, 512, 0, stream>>>(o, projwT, projb, x, n2g, n2b, x1, m);
    mlp_mfma<<<TOK / 64, 256, 0, stream>>>(m, fc1wT, fc1b, fc2wT, fc2b, x1, out);
}